// Round 6
// baseline (215.942 us; speedup 1.0000x reference)
//
#include <hip/hip_runtime.h>

typedef short bf16x8 __attribute__((ext_vector_type(8)));
typedef float f32x4 __attribute__((ext_vector_type(4)));
typedef unsigned short ushort8v __attribute__((ext_vector_type(8)));
typedef unsigned short ushort4v __attribute__((ext_vector_type(4)));

__device__ __forceinline__ unsigned short f2bf(float f) {
  unsigned u = __float_as_uint(f);
  u += 0x7FFF + ((u >> 16) & 1);   // round-to-nearest-even
  return (unsigned short)(u >> 16);
}

// ---------------------------------------------------------------------------
// Kernel 0: weights -> WbT [640][512] bf16, WbT[o][c]:
//   o in [0,64)    = Wq[c][o] * log2(e)   (folds sigmoid exp2 scale into q)
//   o in [64,128)  = Wk[c][o-64]
//   o in [128,640) = Wv[c][o-128]
// ---------------------------------------------------------------------------
__global__ void wt_prep(const float* __restrict__ Wq, const float* __restrict__ Wk,
                        const float* __restrict__ Wv, unsigned short* __restrict__ WbT) {
  int idx = blockIdx.x * 256 + threadIdx.x;   // 640*512 = 327680 total
  int o = idx >> 9, c = idx & 511;
  float v;
  if (o < 64)       v = Wq[c * 64 + o] * 1.44269504f;
  else if (o < 128) v = Wk[c * 64 + (o - 64)];
  else              v = Wv[(size_t)c * 512 + (o - 128)];
  WbT[idx] = f2bf(v);
}

// ---------------------------------------------------------------------------
// Kernel 1: projection GEMM  [16384,512] x [512,640] -> q,k row-major bf16 and
// v transposed vT[b][512][4096] bf16. (validated rounds 3-5, unchanged)
// ---------------------------------------------------------------------------
__global__ __launch_bounds__(256, 2) void proj_gemm(
    const float* __restrict__ x, const unsigned short* __restrict__ WbT,
    unsigned short* __restrict__ q, unsigned short* __restrict__ k,
    unsigned short* __restrict__ vT) {
  __shared__ unsigned short As[128][72];   // 64 + 8 pad
  const int tid = threadIdx.x;
  const int wid = tid >> 6, lane = tid & 63;
  const int l15 = lane & 15, l4 = lane >> 4;
  const int mtile = blockIdx.x, ntile = blockIdx.y;
  const int rbase = mtile * 128;
  const int wr = (wid >> 1) * 64, wc = (wid & 1) * 64;

  f32x4 acc[4][4] = {};

  const int arow = tid >> 2;         // 0..63
  const int akof = (tid & 3) * 16;   // 0,16,32,48

  for (int kb = 0; kb < 512; kb += 64) {
    f32x4 t0[2][4];
#pragma unroll
    for (int pass = 0; pass < 2; ++pass) {
      const float* src = x + (size_t)(rbase + pass * 64 + arow) * 512 + kb + akof;
#pragma unroll
      for (int i = 0; i < 4; ++i) t0[pass][i] = *(const f32x4*)(src + i * 4);
    }
    __syncthreads();   // prior iteration's LDS reads done
#pragma unroll
    for (int pass = 0; pass < 2; ++pass) {
      unsigned short tmp[16];
#pragma unroll
      for (int i = 0; i < 4; ++i)
#pragma unroll
        for (int j = 0; j < 4; ++j) tmp[i * 4 + j] = f2bf(t0[pass][i][j]);
      unsigned short* dst = &As[pass * 64 + arow][akof];
      *(ushort8v*)(dst)     = *(ushort8v*)(tmp);
      *(ushort8v*)(dst + 8) = *(ushort8v*)(tmp + 8);
    }
    __syncthreads();

    bf16x8 af[4][2], bfr[4][2];
#pragma unroll
    for (int mr = 0; mr < 4; ++mr)
#pragma unroll
      for (int ks = 0; ks < 2; ++ks)
        af[mr][ks] = *(const bf16x8*)&As[wr + mr * 16 + l15][ks * 32 + l4 * 8];
#pragma unroll
    for (int nc = 0; nc < 4; ++nc)
#pragma unroll
      for (int ks = 0; ks < 2; ++ks) {
        int col = ntile * 128 + wc + nc * 16 + l15;
        bfr[nc][ks] = *(const bf16x8*)(WbT + (size_t)col * 512 + kb + ks * 32 + l4 * 8);
      }
#pragma unroll
    for (int ks = 0; ks < 2; ++ks)
#pragma unroll
      for (int mr = 0; mr < 4; ++mr)
#pragma unroll
        for (int nc = 0; nc < 4; ++nc)
          acc[mr][nc] = __builtin_amdgcn_mfma_f32_16x16x32_bf16(af[mr][ks], bfr[nc][ks],
                                                                acc[mr][nc], 0, 0, 0);
  }

  if (ntile == 0) {
    unsigned short* dst = (wid & 1) ? k : q;
#pragma unroll
    for (int mr = 0; mr < 4; ++mr)
#pragma unroll
      for (int nc = 0; nc < 4; ++nc)
#pragma unroll
        for (int r = 0; r < 4; ++r) {
          int grow = rbase + wr + mr * 16 + l4 * 4 + r;
          int col = nc * 16 + l15;
          dst[(size_t)grow * 64 + col] = f2bf(acc[mr][nc][r]);
        }
  } else {
#pragma unroll
    for (int mr = 0; mr < 4; ++mr)
#pragma unroll
      for (int nc = 0; nc < 4; ++nc) {
        int col = ntile * 128 + wc + nc * 16 + l15 - 128;   // 0..511
        int grow = rbase + wr + mr * 16 + l4 * 4;
        int b = grow >> 12, m = grow & 4095;
        ushort4v pk;
#pragma unroll
        for (int r = 0; r < 4; ++r) pk[r] = f2bf(acc[mr][nc][r]);
        *(ushort4v*)(vT + ((size_t)b * 512 + col) * 4096 + m) = pk;
      }
  }
}

// ---------------------------------------------------------------------------
// Kernel 2 (v4): fused sigmoid-attention, 2 independent blocks per CU.
// Grid (64 rt, 2 ct, 4 b) = 512 blocks x 256 threads (4 waves) -> 2 blocks/CU
// (55.3 KB LDS each): two independent barrier domains per CU so one block's
// waves issue while the other stalls at its barrier.
// Block output: 64 q-rows x 256 v-cols; m-loop chunks of MB=64.
// S swapped mfma(K,Q): wave w computes m-tile w (16 m) x all 64 rows; sigmoid
// + pack -> b64 P write. PV: wave w takes cols [w*64,+64), all 64 rows.
// 2 barriers/chunk; K ds_write between A and PV; V ds_write after B; global
// loads issued at chunk top (T14). setprio(1) around MFMA clusters (T5).
// ---------------------------------------------------------------------------
__global__ __launch_bounds__(256, 2) void attn_fused(
    const float* __restrict__ x, const unsigned short* __restrict__ q,
    const unsigned short* __restrict__ k, const unsigned short* __restrict__ vT,
    const float* __restrict__ gamma, float* __restrict__ out) {
  __shared__ unsigned short Ks[64][72];    //  9.2 KB  [m][d]
  __shared__ unsigned short Vs[256][72];   // 36.9 KB  [col][m]
  __shared__ unsigned short Ps[64][72];    //  9.2 KB  [row][m]
  const int tid = threadIdx.x, w = tid >> 6, lane = tid & 63;
  const int l15 = lane & 15, l4 = lane >> 4;
  const int rt = blockIdx.x, ct = blockIdx.y, b = blockIdx.z;
  const int rbase = rt * 64, cbase = ct * 256;
  const unsigned short* qb = q + (size_t)b * 4096 * 64;
  const unsigned short* kp = k + (size_t)b * 4096 * 64;
  const unsigned short* vb = vT + (size_t)b * 512 * 4096;
  const float gv = gamma[0];

  // staging assignments (256 threads)
  const int kst_m = tid >> 2, kst_d = (tid & 3) * 16;   // K: 32 B/thread
  const int vst_c = tid;                                 // V: 128 B/thread

  // q fragments: ALL 64 block rows, register-resident (B-operand of mfma(K,Q))
  bf16x8 qf[4][2];
#pragma unroll
  for (int rf = 0; rf < 4; ++rf)
#pragma unroll
    for (int ks = 0; ks < 2; ++ks)
      qf[rf][ks] = *(const bf16x8*)(qb +
          (size_t)(rbase + rf * 16 + l15) * 64 + ks * 32 + l4 * 8);

  // ---- prologue: stage chunk 0 ----
  {
    bf16x8 k0 = *(const bf16x8*)(kp + (size_t)kst_m * 64 + kst_d);
    bf16x8 k1 = *(const bf16x8*)(kp + (size_t)kst_m * 64 + kst_d + 8);
    bf16x8 vv[8];
#pragma unroll
    for (int i = 0; i < 8; ++i)
      vv[i] = *(const bf16x8*)(vb + (size_t)(cbase + vst_c) * 4096 + i * 8);
    *(bf16x8*)&Ks[kst_m][kst_d] = k0;
    *(bf16x8*)&Ks[kst_m][kst_d + 8] = k1;
#pragma unroll
    for (int i = 0; i < 8; ++i) *(bf16x8*)&Vs[vst_c][i * 8] = vv[i];
  }
  __syncthreads();

  f32x4 oacc[4][4] = {};

  for (int it = 0; it < 64; ++it) {
    const int mb_n = (it + 1) * 64;
    const bool pf = (it < 63);
    bf16x8 k0, k1, vv[8];
    if (pf) {   // issue next chunk's global loads early (T14)
      k0 = *(const bf16x8*)(kp + (size_t)(mb_n + kst_m) * 64 + kst_d);
      k1 = *(const bf16x8*)(kp + (size_t)(mb_n + kst_m) * 64 + kst_d + 8);
#pragma unroll
      for (int i = 0; i < 8; ++i)
        vv[i] = *(const bf16x8*)(vb + (size_t)(cbase + vst_c) * 4096 + mb_n + i * 8);
    }

    // ---- S^T = K . Q^T : wave computes m-tile w (16 m) x 64 q-rows ----
    f32x4 sacc[4] = {};
    __builtin_amdgcn_s_setprio(1);
#pragma unroll
    for (int ks = 0; ks < 2; ++ks) {
      bf16x8 kf = *(const bf16x8*)&Ks[w * 16 + l15][ks * 32 + l4 * 8];
#pragma unroll
      for (int rf = 0; rf < 4; ++rf)
        sacc[rf] = __builtin_amdgcn_mfma_f32_16x16x32_bf16(kf, qf[rf][ks], sacc[rf], 0, 0, 0);
    }
    __builtin_amdgcn_s_setprio(0);
    // sigmoid (q pre-scaled by log2e) + pack 4 consecutive m -> b64 write
#pragma unroll
    for (int rf = 0; rf < 4; ++rf) {
      ushort4v pk;
#pragma unroll
      for (int r = 0; r < 4; ++r) {
        float s = sacc[rf][r];
        pk[r] = f2bf(__builtin_amdgcn_rcpf(1.0f + __builtin_amdgcn_exp2f(-s)));
      }
      *(ushort4v*)&Ps[rf * 16 + l15][w * 16 + l4 * 4] = pk;
    }
    __syncthreads();   // A: Ps visible; Ks reads done

    if (pf) {   // next chunk's K (read in next S, after B)
      *(bf16x8*)&Ks[kst_m][kst_d] = k0;
      *(bf16x8*)&Ks[kst_m][kst_d + 8] = k1;
    }

    // ---- O += P . v : wave cols [w*64,+64), all 64 rows ----
#pragma unroll
    for (int kk = 0; kk < 2; ++kk) {
      bf16x8 af[4], bfr[4];
#pragma unroll
      for (int mr = 0; mr < 4; ++mr)
        af[mr] = *(const bf16x8*)&Ps[mr * 16 + l15][kk * 32 + l4 * 8];
#pragma unroll
      for (int nc = 0; nc < 4; ++nc)
        bfr[nc] = *(const bf16x8*)&Vs[w * 64 + nc * 16 + l15][kk * 32 + l4 * 8];
      __builtin_amdgcn_s_setprio(1);
#pragma unroll
      for (int mr = 0; mr < 4; ++mr)
#pragma unroll
        for (int nc = 0; nc < 4; ++nc)
          oacc[mr][nc] = __builtin_amdgcn_mfma_f32_16x16x32_bf16(af[mr], bfr[nc],
                                                                 oacc[mr][nc], 0, 0, 0);
      __builtin_amdgcn_s_setprio(0);
    }
    __syncthreads();   // B: Vs/Ps reads done

    if (pf) {   // next chunk's V (read in next PV, after next A)
#pragma unroll
      for (int i = 0; i < 8; ++i) *(bf16x8*)&Vs[vst_c][i * 8] = vv[i];
    }
  }

  // ---- epilogue: out = gamma * O + x ----
#pragma unroll
  for (int mr = 0; mr < 4; ++mr)
#pragma unroll
    for (int nc = 0; nc < 4; ++nc)
#pragma unroll
      for (int r = 0; r < 4; ++r) {
        int grow = rbase + mr * 16 + l4 * 4 + r;
        int col = cbase + w * 64 + nc * 16 + l15;
        size_t idx = ((size_t)b * 4096 + grow) * 512 + col;
        out[idx] = gv * oacc[mr][nc][r] + x[idx];
      }
}

extern "C" void kernel_launch(void* const* d_in, const int* in_sizes, int n_in,
                              void* d_out, int out_size, void* d_ws, size_t ws_size,
                              hipStream_t stream) {
  const float* x     = (const float*)d_in[0];
  const float* Wq    = (const float*)d_in[1];
  const float* Wk    = (const float*)d_in[2];
  const float* Wv    = (const float*)d_in[3];
  const float* gamma = (const float*)d_in[4];
  float* out = (float*)d_out;

  char* ws = (char*)d_ws;
  unsigned short* qbuf = (unsigned short*)(ws);                       // 2 MB
  unsigned short* kbuf = (unsigned short*)(ws + (2ull << 20));        // 2 MB
  unsigned short* vT   = (unsigned short*)(ws + (4ull << 20));        // 16 MB
  unsigned short* WbT  = (unsigned short*)(ws + (20ull << 20));       // 640 KB

  hipLaunchKernelGGL(wt_prep, dim3(1280), dim3(256), 0, stream, Wq, Wk, Wv, WbT);
  hipLaunchKernelGGL(proj_gemm, dim3(128, 5), dim3(256), 0, stream, x, WbT, qbuf, kbuf, vT);
  hipLaunchKernelGGL(attn_fused, dim3(64, 2, 4), dim3(256), 0, stream,
                     x, qbuf, kbuf, vT, gamma, out);
}

// Round 7
// 150.649 us; speedup vs baseline: 1.4334x; 1.4334x over previous
//
#include <hip/hip_runtime.h>

typedef short bf16x8 __attribute__((ext_vector_type(8)));
typedef float f32x4 __attribute__((ext_vector_type(4)));
typedef unsigned short ushort8v __attribute__((ext_vector_type(8)));
typedef unsigned short ushort4v __attribute__((ext_vector_type(4)));

__device__ __forceinline__ unsigned short f2bf(float f) {
  unsigned u = __float_as_uint(f);
  u += 0x7FFF + ((u >> 16) & 1);   // round-to-nearest-even
  return (unsigned short)(u >> 16);
}

// ---------------------------------------------------------------------------
// Kernel 0: weights -> WbT [640][512] bf16, WbT[o][c]:
//   o in [0,64)    = Wq[c][o] * log2(e)   (folds sigmoid exp2 scale into q)
//   o in [64,128)  = Wk[c][o-64]
//   o in [128,640) = Wv[c][o-128]
// ---------------------------------------------------------------------------
__global__ void wt_prep(const float* __restrict__ Wq, const float* __restrict__ Wk,
                        const float* __restrict__ Wv, unsigned short* __restrict__ WbT) {
  int idx = blockIdx.x * 256 + threadIdx.x;   // 640*512 = 327680 total
  int o = idx >> 9, c = idx & 511;
  float v;
  if (o < 64)       v = Wq[c * 64 + o] * 1.44269504f;
  else if (o < 128) v = Wk[c * 64 + (o - 64)];
  else              v = Wv[(size_t)c * 512 + (o - 128)];
  WbT[idx] = f2bf(v);
}

// ---------------------------------------------------------------------------
// Kernel 1: projection GEMM  [16384,512] x [512,640] -> q,k row-major bf16 and
// v transposed vT[b][512][4096] bf16. (validated rounds 3-6, unchanged)
// ---------------------------------------------------------------------------
__global__ __launch_bounds__(256, 2) void proj_gemm(
    const float* __restrict__ x, const unsigned short* __restrict__ WbT,
    unsigned short* __restrict__ q, unsigned short* __restrict__ k,
    unsigned short* __restrict__ vT) {
  __shared__ unsigned short As[128][72];   // 64 + 8 pad
  const int tid = threadIdx.x;
  const int wid = tid >> 6, lane = tid & 63;
  const int l15 = lane & 15, l4 = lane >> 4;
  const int mtile = blockIdx.x, ntile = blockIdx.y;
  const int rbase = mtile * 128;
  const int wr = (wid >> 1) * 64, wc = (wid & 1) * 64;

  f32x4 acc[4][4] = {};

  const int arow = tid >> 2;         // 0..63
  const int akof = (tid & 3) * 16;   // 0,16,32,48

  for (int kb = 0; kb < 512; kb += 64) {
    f32x4 t0[2][4];
#pragma unroll
    for (int pass = 0; pass < 2; ++pass) {
      const float* src = x + (size_t)(rbase + pass * 64 + arow) * 512 + kb + akof;
#pragma unroll
      for (int i = 0; i < 4; ++i) t0[pass][i] = *(const f32x4*)(src + i * 4);
    }
    __syncthreads();   // prior iteration's LDS reads done
#pragma unroll
    for (int pass = 0; pass < 2; ++pass) {
      unsigned short tmp[16];
#pragma unroll
      for (int i = 0; i < 4; ++i)
#pragma unroll
        for (int j = 0; j < 4; ++j) tmp[i * 4 + j] = f2bf(t0[pass][i][j]);
      unsigned short* dst = &As[pass * 64 + arow][akof];
      *(ushort8v*)(dst)     = *(ushort8v*)(tmp);
      *(ushort8v*)(dst + 8) = *(ushort8v*)(tmp + 8);
    }
    __syncthreads();

    bf16x8 af[4][2], bfr[4][2];
#pragma unroll
    for (int mr = 0; mr < 4; ++mr)
#pragma unroll
      for (int ks = 0; ks < 2; ++ks)
        af[mr][ks] = *(const bf16x8*)&As[wr + mr * 16 + l15][ks * 32 + l4 * 8];
#pragma unroll
    for (int nc = 0; nc < 4; ++nc)
#pragma unroll
      for (int ks = 0; ks < 2; ++ks) {
        int col = ntile * 128 + wc + nc * 16 + l15;
        bfr[nc][ks] = *(const bf16x8*)(WbT + (size_t)col * 512 + kb + ks * 32 + l4 * 8);
      }
#pragma unroll
    for (int ks = 0; ks < 2; ++ks)
#pragma unroll
      for (int mr = 0; mr < 4; ++mr)
#pragma unroll
        for (int nc = 0; nc < 4; ++nc)
          acc[mr][nc] = __builtin_amdgcn_mfma_f32_16x16x32_bf16(af[mr][ks], bfr[nc][ks],
                                                                acc[mr][nc], 0, 0, 0);
  }

  if (ntile == 0) {
    unsigned short* dst = (wid & 1) ? k : q;
#pragma unroll
    for (int mr = 0; mr < 4; ++mr)
#pragma unroll
      for (int nc = 0; nc < 4; ++nc)
#pragma unroll
        for (int r = 0; r < 4; ++r) {
          int grow = rbase + wr + mr * 16 + l4 * 4 + r;
          int col = nc * 16 + l15;
          dst[(size_t)grow * 64 + col] = f2bf(acc[mr][nc][r]);
        }
  } else {
#pragma unroll
    for (int mr = 0; mr < 4; ++mr)
#pragma unroll
      for (int nc = 0; nc < 4; ++nc) {
        int col = ntile * 128 + wc + nc * 16 + l15 - 128;   // 0..511
        int grow = rbase + wr + mr * 16 + l4 * 4;
        int b = grow >> 12, m = grow & 4095;
        ushort4v pk;
#pragma unroll
        for (int r = 0; r < 4; ++r) pk[r] = f2bf(acc[mr][nc][r]);
        *(ushort4v*)(vT + ((size_t)b * 512 + col) * 4096 + m) = pk;
      }
  }
}

// ---------------------------------------------------------------------------
// Kernel 2 (v5): fused sigmoid-attention, ONE barrier per chunk.
// Grid (32 rt, 2 ct, 4 b) = 256 blocks x 512 threads (8 waves), 1 block/CU.
// Block output: 128 q-rows x 256 v-cols; m-loop chunks of MB=64.
// K NEVER in LDS: each S-wave loads its 2 kf fragments direct from global,
// prefetched one chunk ahead into registers (L1/L2-hit, 8 KB/chunk).
// Vs and Ps DOUBLE-buffered -> single barrier per chunk; barrier-to-barrier
// region = PV(it) + S(it+1) + sigmoid(it+1) so MFMA and VALU mix across waves.
// LDS 108 KB. V global loads issued at iter top (T14).
// ---------------------------------------------------------------------------
__global__ __launch_bounds__(512, 1) void attn_fused(
    const float* __restrict__ x, const unsigned short* __restrict__ q,
    const unsigned short* __restrict__ k, const unsigned short* __restrict__ vT,
    const float* __restrict__ gamma, float* __restrict__ out) {
  __shared__ unsigned short Vs[2][256][72];   // 73.7 KB [buf][col][m]
  __shared__ unsigned short Ps[2][128][72];   // 36.9 KB [buf][row][m]
  const int tid = threadIdx.x, w = tid >> 6, lane = tid & 63;
  const int l15 = lane & 15, l4 = lane >> 4;
  const int rhalf = w >> 2;      // 0..1: q-row half (S rows, PV row-group)
  const int mt = w & 3;          // 0..3: m-tile (S) / PV col-group
  const int rt = blockIdx.x, ct = blockIdx.y, b = blockIdx.z;
  const int rbase = rt * 128, cbase = ct * 256;
  const unsigned short* qb = q + (size_t)b * 4096 * 64;
  const unsigned short* kp = k + (size_t)b * 4096 * 64;
  const unsigned short* vb = vT + (size_t)b * 512 * 4096;
  const float gv = gamma[0];

  // V staging: 512 threads x 64 B
  const int vst_c = tid >> 1, vst_h = (tid & 1) * 32;

  // q fragments, register-resident for all 64 chunks
  bf16x8 qf[4][2];
#pragma unroll
  for (int rf = 0; rf < 4; ++rf)
#pragma unroll
    for (int ks = 0; ks < 2; ++ks)
      qf[rf][ks] = *(const bf16x8*)(qb +
          (size_t)(rbase + rhalf * 64 + rf * 16 + l15) * 64 + ks * 32 + l4 * 8);

  // ---- prologue: stage V(0) into Vs[0]; K(0) frags into registers ----
  bf16x8 kfc[2];
#pragma unroll
  for (int ks = 0; ks < 2; ++ks)
    kfc[ks] = *(const bf16x8*)(kp + (size_t)(mt * 16 + l15) * 64 + ks * 32 + l4 * 8);
  {
    bf16x8 vv[4];
#pragma unroll
    for (int i = 0; i < 4; ++i)
      vv[i] = *(const bf16x8*)(vb + (size_t)(cbase + vst_c) * 4096 + vst_h + i * 8);
#pragma unroll
    for (int i = 0; i < 4; ++i) *(bf16x8*)&Vs[0][vst_c][vst_h + i * 8] = vv[i];
  }

  f32x4 oacc[4][4] = {};

  for (int it = 0; it < 64; ++it) {
    const int mb_n = (it + 1) * 64;
    const bool pf = (it < 63);
    const int p = it & 1;
    bf16x8 kfn[2], vv[4];
    if (pf) {   // issue next chunk's global loads early (T14)
#pragma unroll
      for (int ks = 0; ks < 2; ++ks)
        kfn[ks] = *(const bf16x8*)(kp + (size_t)(mb_n + mt * 16 + l15) * 64 + ks * 32 + l4 * 8);
#pragma unroll
      for (int i = 0; i < 4; ++i)
        vv[i] = *(const bf16x8*)(vb + (size_t)(cbase + vst_c) * 4096 + mb_n + vst_h + i * 8);
    }

    // ---- S^T = K.Q^T : wave (rhalf,mt): m-tile mt (16 m) x 64 q-rows ----
    f32x4 sacc[4] = {};
#pragma unroll
    for (int ks = 0; ks < 2; ++ks)
#pragma unroll
      for (int rf = 0; rf < 4; ++rf)
        sacc[rf] = __builtin_amdgcn_mfma_f32_16x16x32_bf16(kfc[ks], qf[rf][ks], sacc[rf], 0, 0, 0);
    // sigmoid (q pre-scaled by log2e) + pack -> b64 P write
#pragma unroll
    for (int rf = 0; rf < 4; ++rf) {
      ushort4v pk;
#pragma unroll
      for (int r = 0; r < 4; ++r) {
        float s = sacc[rf][r];
        pk[r] = f2bf(__builtin_amdgcn_rcpf(1.0f + __builtin_amdgcn_exp2f(-s)));
      }
      *(ushort4v*)&Ps[p][rhalf * 64 + rf * 16 + l15][mt * 16 + l4 * 4] = pk;
    }
    __syncthreads();   // the ONLY barrier per chunk

    // ---- O += P.v : wave rows rhalf*64(+64), cols mt*64(+64) ----
    __builtin_amdgcn_s_setprio(1);
#pragma unroll
    for (int kk = 0; kk < 2; ++kk) {
      bf16x8 af[4], bfr[4];
#pragma unroll
      for (int mr = 0; mr < 4; ++mr)
        af[mr] = *(const bf16x8*)&Ps[p][rhalf * 64 + mr * 16 + l15][kk * 32 + l4 * 8];
#pragma unroll
      for (int nc = 0; nc < 4; ++nc)
        bfr[nc] = *(const bf16x8*)&Vs[p][mt * 64 + nc * 16 + l15][kk * 32 + l4 * 8];
#pragma unroll
      for (int mr = 0; mr < 4; ++mr)
#pragma unroll
        for (int nc = 0; nc < 4; ++nc)
          oacc[mr][nc] = __builtin_amdgcn_mfma_f32_16x16x32_bf16(af[mr], bfr[nc],
                                                                 oacc[mr][nc], 0, 0, 0);
    }
    __builtin_amdgcn_s_setprio(0);

    if (pf) {   // write next chunk's V into other buffer; rotate K frags
#pragma unroll
      for (int i = 0; i < 4; ++i) *(bf16x8*)&Vs[p ^ 1][vst_c][vst_h + i * 8] = vv[i];
      kfc[0] = kfn[0]; kfc[1] = kfn[1];
    }
  }

  // ---- epilogue: out = gamma * O + x ----
#pragma unroll
  for (int mr = 0; mr < 4; ++mr)
#pragma unroll
    for (int nc = 0; nc < 4; ++nc)
#pragma unroll
      for (int r = 0; r < 4; ++r) {
        int grow = rbase + rhalf * 64 + mr * 16 + l4 * 4 + r;
        int col = cbase + mt * 64 + nc * 16 + l15;
        size_t idx = ((size_t)b * 4096 + grow) * 512 + col;
        out[idx] = gv * oacc[mr][nc][r] + x[idx];
      }
}

extern "C" void kernel_launch(void* const* d_in, const int* in_sizes, int n_in,
                              void* d_out, int out_size, void* d_ws, size_t ws_size,
                              hipStream_t stream) {
  const float* x     = (const float*)d_in[0];
  const float* Wq    = (const float*)d_in[1];
  const float* Wk    = (const float*)d_in[2];
  const float* Wv    = (const float*)d_in[3];
  const float* gamma = (const float*)d_in[4];
  float* out = (float*)d_out;

  char* ws = (char*)d_ws;
  unsigned short* qbuf = (unsigned short*)(ws);                       // 2 MB
  unsigned short* kbuf = (unsigned short*)(ws + (2ull << 20));        // 2 MB
  unsigned short* vT   = (unsigned short*)(ws + (4ull << 20));        // 16 MB
  unsigned short* WbT  = (unsigned short*)(ws + (20ull << 20));       // 640 KB

  hipLaunchKernelGGL(wt_prep, dim3(1280), dim3(256), 0, stream, Wq, Wk, Wv, WbT);
  hipLaunchKernelGGL(proj_gemm, dim3(128, 5), dim3(256), 0, stream, x, WbT, qbuf, kbuf, vT);
  hipLaunchKernelGGL(attn_fused, dim3(32, 2, 4), dim3(512), 0, stream,
                     x, qbuf, kbuf, vT, gamma, out);
}